// Round 22
// baseline (129.076 us; speedup 1.0000x reference)
//
#include <hip/hip_runtime.h>

// irreps: 256x0e + 128x1e + 64x2e ; x row = 960 fp32
// R22 = R21 (best: 119.5us, nt stores) with the occupancy<->tile trade
// re-tested at the new operating point: l=0 ROWS 128->64 (32KB) so the
// merged kernel's LDS = 48KB (l=1's size) -> 3 blocks/CU for ALL types
// (+50% TLP), launch_bounds(256,3). Cost: l=0 B:MFMA amortization 1:8->1:4.
// Everything else identical: nt output stores, XOR-swizzled LDS, distance-1
// B prefetch, 3 barriers/tile, XCD-aware tile swizzle per type range.

typedef __bf16 v8bf  __attribute__((ext_vector_type(8)));
typedef __bf16 v2bf  __attribute__((ext_vector_type(2)));
typedef float  v4f   __attribute__((ext_vector_type(4)));

__device__ __forceinline__ unsigned short bfbits(float x) {
    __bf16 h = (__bf16)x;
    return __builtin_bit_cast(unsigned short, h);
}

// Phi(n) = 0.5*(1+erf(n/sqrt(2))) = gelu(n)/n, n>=0.  A&S 7.1.26.
__device__ __forceinline__ float phi_from_n(float n) {
    float z = n * 0.70710678118654752f;
    float t = __builtin_amdgcn_rcpf(fmaf(0.3275911f, z, 1.0f));
    float p = t * fmaf(t, fmaf(t, fmaf(t, fmaf(t, 1.061405429f, -1.453152027f),
                                       1.421413741f), -0.284496736f), 0.254829592f);
    float e = __builtin_amdgcn_exp2f(z * z * -1.4426950408889634f);
    return fmaf(p * e, -0.5f, 1.0f);
}

// --- pre-pass: W[u][w] fp32 -> WT[w][u] bf16, scaled by 1/sqrt(mul_in) -------
__global__ __launch_bounds__(256) void wt_prep(
    const float* __restrict__ w0, const float* __restrict__ w1,
    const float* __restrict__ w2, const float* __restrict__ w3,
    const float* __restrict__ w4, const float* __restrict__ w5,
    unsigned short* __restrict__ out)
{
    int t = blockIdx.x * 256 + threadIdx.x;
    if (t >= 172032) return;
    int s = (t < 65536) ? 0 : (t < 81920) ? 1 : (t < 86016) ? 2
          : (t < 151552) ? 3 : (t < 167936) ? 4 : 5;
    int base = (s == 0) ? 0 : (s == 1) ? 65536 : (s == 2) ? 81920
             : (s == 3) ? 86016 : (s == 4) ? 151552 : 167936;
    int lg   = (s == 0 || s == 3) ? 8 : (s == 1 || s == 4) ? 7 : 6;
    float scl = (s == 0 || s == 3) ? 0.0625f
              : (s == 1 || s == 4) ? 0.08838834764831845f : 0.125f;
    const float* p = (s == 0) ? w0 : (s == 1) ? w1 : (s == 2) ? w2
                   : (s == 3) ? w3 : (s == 4) ? w4 : w5;
    int loc = t - base;
    int w = loc >> lg;
    int u = loc & ((1 << lg) - 1);
    out[t] = bfbits(p[(u << lg) + w] * scl);
}

// --- per-irrep worker (ROWS-row tile) ----------------------------------------
// LDS: bf16 planes [i][n(ROWS)][u(U)], XOR-swizzled idx ^= (R&7)<<3, R=i*ROWS+n.
template<int U, int D, int OFF, int ROWS>
__device__ __forceinline__ void irrep_block(
    const float* __restrict__ x,
    const unsigned short* __restrict__ wt0,
    const unsigned short* __restrict__ wt1,
    float* __restrict__ out,
    unsigned short* __restrict__ lds,
    int tile)
{
    constexpr int MT   = (ROWS * D) / 16;   // m-tiles
    constexpr int NPW  = U / 64;            // n-tiles per wave (4 waves split n)
    constexpr int KT   = U / 32;            // k-steps
    constexpr int NR16 = ROWS / 16;         // 16-row groups per i-plane
    static_assert(ROWS * D * U <= 24576, "LDS overflow");

    const int tid  = threadIdx.x;
    const int lane = tid & 63;
    const int wid  = tid >> 6;
    const int row0 = tile * ROWS;
    const int wcol = lane & 15;
    const int kcol = (lane >> 4) << 3;
    const int g4   = (lane >> 4) << 2;

    // ---- stage x -> LDS bf16, de-interleaved [i*ROWS+n][u] ----
    if constexpr (D == 1) {
        #pragma unroll
        for (int o = 0; o < (ROWS * (U / 8)) / 256; ++o) {
            int oct = o * 256 + tid;
            int row = oct / (U / 8);
            int u0  = (oct % (U / 8)) * 8;
            const float4* p =
                reinterpret_cast<const float4*>(x + (long)(row0 + row) * 960 + OFF + u0);
            float4 fa = p[0], fb = p[1];
            v8bf hv = { (__bf16)fa.x, (__bf16)fa.y, (__bf16)fa.z, (__bf16)fa.w,
                        (__bf16)fb.x, (__bf16)fb.y, (__bf16)fb.z, (__bf16)fb.w };
            int idx = (row * U + u0) ^ ((row & 7) << 3);
            *reinterpret_cast<v8bf*>(&lds[idx]) = hv;
        }
    } else {
        constexpr int PAIRS = U / 2;
        #pragma unroll
        for (int g = 0; g < (ROWS * PAIRS) / 256; ++g) {
            int gid = g * 256 + tid;
            int row = gid / PAIRS;
            int u0  = (gid % PAIRS) * 2;
            const float2* p = reinterpret_cast<const float2*>(
                x + (long)(row0 + row) * 960 + OFF + u0 * D);
            float f[2 * D];
            #pragma unroll
            for (int j = 0; j < D; ++j) { float2 q = p[j]; f[2*j] = q.x; f[2*j+1] = q.y; }
            #pragma unroll
            for (int i = 0; i < D; ++i) {
                int R = i * ROWS + row;
                int idx = (R * U + u0) ^ ((R & 7) << 3);
                v2bf h2 = { (__bf16)f[i], (__bf16)f[D + i] };
                *reinterpret_cast<v2bf*>(&lds[idx]) = h2;
            }
        }
    }

    v4f acc[MT][NPW];
    v8bf bpre[NPW];

    auto issueB = [&](const unsigned short* __restrict__ wt, int kt) {
        #pragma unroll
        for (int nt = 0; nt < NPW; ++nt) {
            int w = (wid * NPW + nt) * 16 + wcol;
            bpre[nt] = *reinterpret_cast<const v8bf*>(wt + w * U + kt * 32 + kcol);
        }
    };

    auto run_layer = [&](const unsigned short* __restrict__ wt) {
        #pragma unroll
        for (int mt = 0; mt < MT; ++mt)
            #pragma unroll
            for (int nt = 0; nt < NPW; ++nt) {
                v4f z = {0.f, 0.f, 0.f, 0.f};
                acc[mt][nt] = z;
            }
        #pragma unroll
        for (int kt = 0; kt < KT; ++kt) {
            v8bf bcur[NPW];
            #pragma unroll
            for (int nt = 0; nt < NPW; ++nt) bcur[nt] = bpre[nt];
            if (kt + 1 < KT) issueB(wt, kt + 1);
            #pragma unroll
            for (int mt = 0; mt < MT; ++mt) {
                int R = mt * 16 + wcol;
                int idx = (R * U + kt * 32 + kcol) ^ ((R & 7) << 3);
                v8bf a = *reinterpret_cast<const v8bf*>(&lds[idx]);
                #pragma unroll
                for (int nt = 0; nt < NPW; ++nt)
                    acc[mt][nt] = __builtin_amdgcn_mfma_f32_16x16x32_bf16(
                        a, bcur[nt], acc[mt][nt], 0, 0, 0);
            }
        }
    };

    issueB(wt0, 0);      // L2 round trip overlaps staging + barrier skew
    __syncthreads();     // stage visible

    run_layer(wt0);
    __syncthreads();     // all layer-1 LDS reads done before H overwrites x

    issueB(wt1, 0);      // layer-2 kstep-0 B flies under normact

    // ---- norm-act: acc[i*NR16+h][nt][r] holds component i of row (h*16+g4+r) ----
    #pragma unroll
    for (int nt = 0; nt < NPW; ++nt) {
        int w = (wid * NPW + nt) * 16 + wcol;
        #pragma unroll
        for (int h = 0; h < NR16; ++h) {
            #pragma unroll
            for (int r = 0; r < 4; ++r) {
                float n;
                if constexpr (D == 1) {
                    n = __builtin_fabsf(acc[h][nt][r]);
                } else {
                    float s = 0.f;
                    #pragma unroll
                    for (int i = 0; i < D; ++i) {
                        float v = acc[i * NR16 + h][nt][r];
                        s += v * v;
                    }
                    n = __builtin_amdgcn_sqrtf(s);
                }
                float fac = phi_from_n(n);
                int nr = h * 16 + g4 + r;
                #pragma unroll
                for (int i = 0; i < D; ++i) {
                    int R = i * ROWS + nr;
                    int idx = (R * U + w) ^ ((R & 7) << 3);
                    lds[idx] = bfbits(acc[i * NR16 + h][nt][r] * fac);
                }
            }
        }
    }
    __syncthreads();     // H visible

    run_layer(wt1);

    // ---- store fp32 at out[n][OFF + w*D + i]; NON-TEMPORAL ----
    #pragma unroll
    for (int nt = 0; nt < NPW; ++nt) {
        int w = (wid * NPW + nt) * 16 + wcol;
        #pragma unroll
        for (int h = 0; h < NR16; ++h) {
            #pragma unroll
            for (int r = 0; r < 4; ++r) {
                int n = row0 + h * 16 + g4 + r;
                float* po = out + (long)n * 960 + OFF + w * D;
                #pragma unroll
                for (int i = 0; i < D; ++i)
                    __builtin_nontemporal_store(acc[i * NR16 + h][nt][r], po + i);
            }
        }
    }
}

// XCD-aware swizzle within a type range of size N (N % 8 == 0):
// dispatched block b (round-robins XCD = b%8) -> tile (b&7)*(N/8) + b/8,
// so each XCD's L2 serves a contiguous x/out segment.
__device__ __forceinline__ int xcd_swz(int b, int N) {
    return (b & 7) * (N >> 3) + (b >> 3);
}

// --- merged kernel: contiguous type ranges + XCD swizzle ---------------------
// bid 0..1023    : l=0, 64-row tiles (32 KB)
// bid 1024..2047 : l=1, 64-row tiles (48 KB)
// bid 2048..3071 : l=2, 64-row tiles (40 KB)
__global__ __launch_bounds__(256, 3) void fused_all(
    const float* __restrict__ x,
    const unsigned short* __restrict__ ws,
    float* __restrict__ out)
{
    __shared__ unsigned short lds[24576];   // 48 KB (max over the 3 types)
    int bid = blockIdx.x;
    if (bid < 1024)
        irrep_block<256, 1,   0, 64>(x, ws + 0,     ws + 86016,  out, lds,
                                     xcd_swz(bid, 1024));
    else if (bid < 2048)
        irrep_block<128, 3, 256, 64>(x, ws + 65536, ws + 151552, out, lds,
                                     xcd_swz(bid - 1024, 1024));
    else
        irrep_block< 64, 5, 640, 64>(x, ws + 81920, ws + 167936, out, lds,
                                     xcd_swz(bid - 2048, 1024));
}

extern "C" void kernel_launch(void* const* d_in, const int* in_sizes, int n_in,
                              void* d_out, int out_size, void* d_ws, size_t ws_size,
                              hipStream_t stream)
{
    const float* x  = (const float*)d_in[0];
    const float* W0 = (const float*)d_in[1];  // 256x256
    const float* W1 = (const float*)d_in[2];  // 128x128
    const float* W2 = (const float*)d_in[3];  // 64x64
    const float* W3 = (const float*)d_in[4];  // 256x256
    const float* W4 = (const float*)d_in[5];  // 128x128
    const float* W5 = (const float*)d_in[6];  // 64x64
    unsigned short* ws = (unsigned short*)d_ws;   // 344064 B of bf16 WT
    float* out = (float*)d_out;

    wt_prep<<<672, 256, 0, stream>>>(W0, W1, W2, W3, W4, W5, ws);
    fused_all<<<3072, 256, 0, stream>>>(x, ws, out);
}

// Round 23
// 117.441 us; speedup vs baseline: 1.0991x; 1.0991x over previous
//
#include <hip/hip_runtime.h>

// irreps: 256x0e + 128x1e + 64x2e ; x row = 960 fp32
// R23 = R21 (best: 119.5us) + nt-store loop reorder: issue the 4 adjacent
// 64B chunks of each wave's contiguous 256B output region back-to-back
// (nt innermost) so the memory-controller write combiner assembles full
// lines -- nt stores bypass L2 aggregation, so instruction adjacency is
// what determines line assembly. R22 (3 blk/CU, small l=0 tiles) regressed:
// per-tile amortization > TLP, confirmed 5x.
// Structure: merged fused linear->normact->linear, bf16 MFMA;
// l=0 128-row (64KB LDS) / l=1 64-row (48KB) / l=2 64-row (40KB) tiles;
// XOR-swizzled LDS, distance-1 B prefetch, 3 barriers/tile, XCD swizzle,
// non-temporal output stores, __launch_bounds__(256,2).

typedef __bf16 v8bf  __attribute__((ext_vector_type(8)));
typedef __bf16 v2bf  __attribute__((ext_vector_type(2)));
typedef float  v4f   __attribute__((ext_vector_type(4)));

__device__ __forceinline__ unsigned short bfbits(float x) {
    __bf16 h = (__bf16)x;
    return __builtin_bit_cast(unsigned short, h);
}

// Phi(n) = 0.5*(1+erf(n/sqrt(2))) = gelu(n)/n, n>=0.  A&S 7.1.26.
__device__ __forceinline__ float phi_from_n(float n) {
    float z = n * 0.70710678118654752f;
    float t = __builtin_amdgcn_rcpf(fmaf(0.3275911f, z, 1.0f));
    float p = t * fmaf(t, fmaf(t, fmaf(t, fmaf(t, 1.061405429f, -1.453152027f),
                                       1.421413741f), -0.284496736f), 0.254829592f);
    float e = __builtin_amdgcn_exp2f(z * z * -1.4426950408889634f);
    return fmaf(p * e, -0.5f, 1.0f);
}

// --- pre-pass: W[u][w] fp32 -> WT[w][u] bf16, scaled by 1/sqrt(mul_in) -------
__global__ __launch_bounds__(256) void wt_prep(
    const float* __restrict__ w0, const float* __restrict__ w1,
    const float* __restrict__ w2, const float* __restrict__ w3,
    const float* __restrict__ w4, const float* __restrict__ w5,
    unsigned short* __restrict__ out)
{
    int t = blockIdx.x * 256 + threadIdx.x;
    if (t >= 172032) return;
    int s = (t < 65536) ? 0 : (t < 81920) ? 1 : (t < 86016) ? 2
          : (t < 151552) ? 3 : (t < 167936) ? 4 : 5;
    int base = (s == 0) ? 0 : (s == 1) ? 65536 : (s == 2) ? 81920
             : (s == 3) ? 86016 : (s == 4) ? 151552 : 167936;
    int lg   = (s == 0 || s == 3) ? 8 : (s == 1 || s == 4) ? 7 : 6;
    float scl = (s == 0 || s == 3) ? 0.0625f
              : (s == 1 || s == 4) ? 0.08838834764831845f : 0.125f;
    const float* p = (s == 0) ? w0 : (s == 1) ? w1 : (s == 2) ? w2
                   : (s == 3) ? w3 : (s == 4) ? w4 : w5;
    int loc = t - base;
    int w = loc >> lg;
    int u = loc & ((1 << lg) - 1);
    out[t] = bfbits(p[(u << lg) + w] * scl);
}

// --- per-irrep worker (ROWS-row tile) ----------------------------------------
// LDS: bf16 planes [i][n(ROWS)][u(U)], XOR-swizzled idx ^= (R&7)<<3, R=i*ROWS+n.
template<int U, int D, int OFF, int ROWS>
__device__ __forceinline__ void irrep_block(
    const float* __restrict__ x,
    const unsigned short* __restrict__ wt0,
    const unsigned short* __restrict__ wt1,
    float* __restrict__ out,
    unsigned short* __restrict__ lds,
    int tile)
{
    constexpr int MT   = (ROWS * D) / 16;   // m-tiles
    constexpr int NPW  = U / 64;            // n-tiles per wave (4 waves split n)
    constexpr int KT   = U / 32;            // k-steps
    constexpr int NR16 = ROWS / 16;         // 16-row groups per i-plane
    static_assert(ROWS * D * U <= 32768, "LDS overflow");

    const int tid  = threadIdx.x;
    const int lane = tid & 63;
    const int wid  = tid >> 6;
    const int row0 = tile * ROWS;
    const int wcol = lane & 15;
    const int kcol = (lane >> 4) << 3;
    const int g4   = (lane >> 4) << 2;

    // ---- stage x -> LDS bf16, de-interleaved [i*ROWS+n][u] ----
    if constexpr (D == 1) {
        #pragma unroll
        for (int o = 0; o < (ROWS * (U / 8)) / 256; ++o) {
            int oct = o * 256 + tid;
            int row = oct / (U / 8);
            int u0  = (oct % (U / 8)) * 8;
            const float4* p =
                reinterpret_cast<const float4*>(x + (long)(row0 + row) * 960 + OFF + u0);
            float4 fa = p[0], fb = p[1];
            v8bf hv = { (__bf16)fa.x, (__bf16)fa.y, (__bf16)fa.z, (__bf16)fa.w,
                        (__bf16)fb.x, (__bf16)fb.y, (__bf16)fb.z, (__bf16)fb.w };
            int idx = (row * U + u0) ^ ((row & 7) << 3);
            *reinterpret_cast<v8bf*>(&lds[idx]) = hv;
        }
    } else {
        constexpr int PAIRS = U / 2;
        #pragma unroll
        for (int g = 0; g < (ROWS * PAIRS) / 256; ++g) {
            int gid = g * 256 + tid;
            int row = gid / PAIRS;
            int u0  = (gid % PAIRS) * 2;
            const float2* p = reinterpret_cast<const float2*>(
                x + (long)(row0 + row) * 960 + OFF + u0 * D);
            float f[2 * D];
            #pragma unroll
            for (int j = 0; j < D; ++j) { float2 q = p[j]; f[2*j] = q.x; f[2*j+1] = q.y; }
            #pragma unroll
            for (int i = 0; i < D; ++i) {
                int R = i * ROWS + row;
                int idx = (R * U + u0) ^ ((R & 7) << 3);
                v2bf h2 = { (__bf16)f[i], (__bf16)f[D + i] };
                *reinterpret_cast<v2bf*>(&lds[idx]) = h2;
            }
        }
    }

    v4f acc[MT][NPW];
    v8bf bpre[NPW];

    auto issueB = [&](const unsigned short* __restrict__ wt, int kt) {
        #pragma unroll
        for (int nt = 0; nt < NPW; ++nt) {
            int w = (wid * NPW + nt) * 16 + wcol;
            bpre[nt] = *reinterpret_cast<const v8bf*>(wt + w * U + kt * 32 + kcol);
        }
    };

    auto run_layer = [&](const unsigned short* __restrict__ wt) {
        #pragma unroll
        for (int mt = 0; mt < MT; ++mt)
            #pragma unroll
            for (int nt = 0; nt < NPW; ++nt) {
                v4f z = {0.f, 0.f, 0.f, 0.f};
                acc[mt][nt] = z;
            }
        #pragma unroll
        for (int kt = 0; kt < KT; ++kt) {
            v8bf bcur[NPW];
            #pragma unroll
            for (int nt = 0; nt < NPW; ++nt) bcur[nt] = bpre[nt];
            if (kt + 1 < KT) issueB(wt, kt + 1);
            #pragma unroll
            for (int mt = 0; mt < MT; ++mt) {
                int R = mt * 16 + wcol;
                int idx = (R * U + kt * 32 + kcol) ^ ((R & 7) << 3);
                v8bf a = *reinterpret_cast<const v8bf*>(&lds[idx]);
                #pragma unroll
                for (int nt = 0; nt < NPW; ++nt)
                    acc[mt][nt] = __builtin_amdgcn_mfma_f32_16x16x32_bf16(
                        a, bcur[nt], acc[mt][nt], 0, 0, 0);
            }
        }
    };

    issueB(wt0, 0);      // L2 round trip overlaps staging + barrier skew
    __syncthreads();     // stage visible

    run_layer(wt0);
    __syncthreads();     // all layer-1 LDS reads done before H overwrites x

    issueB(wt1, 0);      // layer-2 kstep-0 B flies under normact

    // ---- norm-act: acc[i*NR16+h][nt][r] holds component i of row (h*16+g4+r) ----
    #pragma unroll
    for (int nt = 0; nt < NPW; ++nt) {
        int w = (wid * NPW + nt) * 16 + wcol;
        #pragma unroll
        for (int h = 0; h < NR16; ++h) {
            #pragma unroll
            for (int r = 0; r < 4; ++r) {
                float n;
                if constexpr (D == 1) {
                    n = __builtin_fabsf(acc[h][nt][r]);
                } else {
                    float s = 0.f;
                    #pragma unroll
                    for (int i = 0; i < D; ++i) {
                        float v = acc[i * NR16 + h][nt][r];
                        s += v * v;
                    }
                    n = __builtin_amdgcn_sqrtf(s);
                }
                float fac = phi_from_n(n);
                int nr = h * 16 + g4 + r;
                #pragma unroll
                for (int i = 0; i < D; ++i) {
                    int R = i * ROWS + nr;
                    int idx = (R * U + w) ^ ((R & 7) << 3);
                    lds[idx] = bfbits(acc[i * NR16 + h][nt][r] * fac);
                }
            }
        }
    }
    __syncthreads();     // H visible

    run_layer(wt1);

    // ---- store fp32, NON-TEMPORAL, nt-innermost so each wave's adjacent
    // 64B chunks (256B region) issue back-to-back for write combining ----
    #pragma unroll
    for (int h = 0; h < NR16; ++h) {
        #pragma unroll
        for (int r = 0; r < 4; ++r) {
            int n = row0 + h * 16 + g4 + r;
            #pragma unroll
            for (int nt = 0; nt < NPW; ++nt) {
                int w = (wid * NPW + nt) * 16 + wcol;
                float* po = out + (long)n * 960 + OFF + w * D;
                #pragma unroll
                for (int i = 0; i < D; ++i)
                    __builtin_nontemporal_store(acc[i * NR16 + h][nt][r], po + i);
            }
        }
    }
}

// XCD-aware swizzle within a type range of size N (N % 8 == 0):
// dispatched block b (round-robins XCD = b%8) -> tile (b&7)*(N/8) + b/8,
// so each XCD's L2 serves a contiguous x/out segment.
__device__ __forceinline__ int xcd_swz(int b, int N) {
    return (b & 7) * (N >> 3) + (b >> 3);
}

// --- merged kernel: contiguous type ranges + XCD swizzle ---------------------
// bid 0..511     : l=0, 128-row tiles
// bid 512..1535  : l=1,  64-row tiles
// bid 1536..2559 : l=2,  64-row tiles
__global__ __launch_bounds__(256, 2) void fused_all(
    const float* __restrict__ x,
    const unsigned short* __restrict__ ws,
    float* __restrict__ out)
{
    __shared__ unsigned short lds[32768];   // 64 KB (max over the 3 types)
    int bid = blockIdx.x;
    if (bid < 512)
        irrep_block<256, 1,   0, 128>(x, ws + 0,     ws + 86016,  out, lds,
                                      xcd_swz(bid, 512));
    else if (bid < 1536)
        irrep_block<128, 3, 256,  64>(x, ws + 65536, ws + 151552, out, lds,
                                      xcd_swz(bid - 512, 1024));
    else
        irrep_block< 64, 5, 640,  64>(x, ws + 81920, ws + 167936, out, lds,
                                      xcd_swz(bid - 1536, 1024));
}

extern "C" void kernel_launch(void* const* d_in, const int* in_sizes, int n_in,
                              void* d_out, int out_size, void* d_ws, size_t ws_size,
                              hipStream_t stream)
{
    const float* x  = (const float*)d_in[0];
    const float* W0 = (const float*)d_in[1];  // 256x256
    const float* W1 = (const float*)d_in[2];  // 128x128
    const float* W2 = (const float*)d_in[3];  // 64x64
    const float* W3 = (const float*)d_in[4];  // 256x256
    const float* W4 = (const float*)d_in[5];  // 128x128
    const float* W5 = (const float*)d_in[6];  // 64x64
    unsigned short* ws = (unsigned short*)d_ws;   // 344064 B of bf16 WT
    float* out = (float*)d_out;

    wt_prep<<<672, 256, 0, stream>>>(W0, W1, W2, W3, W4, W5, ws);
    fused_all<<<2560, 256, 0, stream>>>(x, ws, out);
}